// Round 7
// baseline (286.415 us; speedup 1.0000x reference)
//
#include <hip/hip_runtime.h>

// MVDR oracle beamformer — MI355X (gfx950)
// R7: request-shape experiment, final granularity doubling.
//   Evidence: cov plateaued 103->84->77 us as wave-granule went 128->256->512B;
//   working set is L3-resident at steady state (FETCH 77.6 < 158 MB logical)
//   yet delivery is only ~2 TB/s. The untested shape is the m13 copy-bench
//   shape: float4, 1 KB/wave-instr. Slab = 4t so each plane span is exactly
//   257 float4 (4112 B contiguous, 16B-aligned). LDS dbuf [2][16][1028]
//   = 131.6 KB (m201 precedent: >64KB static LDS OK on gfx950), 1 block/CU.
//   Also: SBAR-pinned MLP for reduce_cov (batches of 10) and beamform
//   (all 16 mix float4 issued before use) — both were sink-to-use limited.
// solve_w: R6 wave-parallel version (kept).

constexpr int N_  = 8;
constexpr int C_  = 8;
constexpr int T_  = 600;
constexpr int F_  = 257;
constexpr int TF_  = T_ * F_;       // 154200
constexpr int CTF_ = C_ * TF_;      // 1233600
constexpr int NSTR_ = 2 * CTF_;     // per-batch stride in inputs
constexpr int NF_  = N_ * F_;       // 2056
constexpr int NPAIR_ = 36;          // lower-triangle pairs of 8x8 Hermitian
constexpr float LOADC_ = 7.0710678118654755e-4f;  // 0.001/sqrt(2)
constexpr float INV_T_ = 1.0f / 600.0f;

#define SBAR() __builtin_amdgcn_sched_barrier(0)

struct cx { float r, i; };
__device__ __forceinline__ cx cmul(cx a, cx b) { return {a.r*b.r - a.i*b.i, a.r*b.i + a.i*b.r}; }
__device__ __forceinline__ cx csub(cx a, cx b) { return {a.r - b.r, a.i - b.i}; }
__device__ __forceinline__ cx cinv(cx a) {
    float id = 1.0f / (a.r*a.r + a.i*a.i);
    return {a.r*id, -a.i*id};
}

// ---------------------------------------------------------------------------
// Phase A. grid (TSPLIT, N, 2), block 320 (5 waves).
// Slab = 4 consecutive t (t0 % 4 == 0), 16 planes (re c=0..7, im c=0..7).
// Per plane: CONTIGUOUS 1028-float span = 257 float4, 16B-aligned always
// (plane base 616800c B, t-offset 4112*(t0/4) B). 4112 float4 units staged
// cooperatively, 13/thread (units >= 4112 wrap -> benign dup load+write).
// LDS S[2][16][1028] (131.6 KB) double-buffered, 1 block/CU, 65.8 KB in
// flight per CU during compute. Partial layout unchanged:
//   part[((m*TSPLIT+chunk)*72 + 2p+ri)*NF + n*F + f]
// ---------------------------------------------------------------------------
template<int TSPLIT>
__global__ __launch_bounds__(320, 1) void cov_partial(
        const float* __restrict__ mix, const float* __restrict__ noi,
        float* __restrict__ part) {
    constexpr int TCHUNK = T_ / TSPLIT;
    static_assert(TCHUNK % 4 == 0, "4t slabs need TCHUNK % 4 == 0");
    constexpr int NS = TCHUNK / 4;
    constexpr int NE4 = 16 * 257;           // float4 units per slab: 4112
    constexpr int KU = 13;                  // ceil(4112/320)

    __shared__ float S[2][16][1028];        // 131584 B

    const int tid = threadIdx.x;
    const int chunk = blockIdx.x;
    const int n = blockIdx.y;
    const int m = blockIdx.z;
    const float* src = (m ? mix : noi) + (size_t)n * NSTR_;
    const int tBase = chunk * TCHUNK;

    float4 rg[KU];
    auto stage = [&](int t0) {              // 13 x 16B loads, 4KB spans
        const size_t tF = (size_t)t0 * 257;
#pragma unroll
        for (int kk = 0; kk < KU; ++kk) {
            int u = tid + 320 * kk; int e = (u >= NE4) ? u - NE4 : u;
            int pl = e / 257; int r = e - pl * 257;
            int c = pl & 7;
            size_t goff = ((pl < 8) ? (size_t)c * TF_
                                    : (size_t)CTF_ + (size_t)c * TF_) + 4 * r;
            rg[kk] = *(const float4*)(src + goff + tF);
        }
    };
    auto writeL = [&](int buf) {            // vmcnt waits land here (late)
        float* b = &S[buf][0][0];
#pragma unroll
        for (int kk = 0; kk < KU; ++kk) {
            int u = tid + 320 * kk; int e = (u >= NE4) ? u - NE4 : u;
            int pl = e / 257; int r = e - pl * 257;
            *(float4*)(b + pl * 1028 + 4 * r) = rg[kk];
        }
    };

    float accr[NPAIR_], acci[NPAIR_];
#pragma unroll
    for (int p = 0; p < NPAIR_; ++p) { accr[p] = 0.f; acci[p] = 0.f; }

    auto consume = [&](int buf) {
        if (tid < F_) {
#pragma unroll
            for (int tt = 0; tt < 4; ++tt) {   // t ascending (same FP order)
                float re[C_], im[C_];
#pragma unroll
                for (int c = 0; c < C_; ++c) {
                    re[c] = S[buf][c][tt * 257 + tid];
                    im[c] = S[buf][8 + c][tt * 257 + tid];
                }
                int p = 0;
#pragma unroll
                for (int c = 0; c < C_; ++c) {
#pragma unroll
                    for (int d = 0; d <= c; ++d, ++p) {
                        accr[p] += re[c]*re[d] + im[c]*im[d];
                        acci[p] += im[c]*re[d] - re[c]*im[d];
                    }
                }
            }
        }
    };

    stage(tBase); SBAR();
    writeL(0);
    __syncthreads();

    for (int k = 0; k < NS; ++k) {
        const bool more = (k + 1 < NS);
        if (more) { stage(tBase + 4 * (k + 1)); SBAR(); }  // issue-early
        consume(k & 1);
        SBAR();                      // keep writeL's vmcnt stall AFTER FMAs
        if (more) writeL((k + 1) & 1);
        __syncthreads();
    }

    if (tid < F_) {
        float* out = part + (size_t)((m * TSPLIT + chunk) * 72) * NF_ + n * F_ + tid;
#pragma unroll
        for (int p = 0; p < NPAIR_; ++p) {
            out[(size_t)(2*p)   * NF_] = accr[p];
            out[(size_t)(2*p+1) * NF_] = acci[p];
        }
    }
}

// ---------------------------------------------------------------------------
// Phase B1: chunk reduction, float4, SBAR-pinned batches of 10 (MLP fix:
// previous version was sink-to-use at 4.5 waves/CU -> latency-exposed).
// ---------------------------------------------------------------------------
__global__ __launch_bounds__(256) void reduce_cov(float* __restrict__ part, int tsplit) {
    int flat = blockIdx.x * 256 + threadIdx.x;
    constexpr int NQ4 = NF_ / 4;   // 514
    if (flat >= 2 * 72 * NQ4) return;
    int idx4 = flat % NQ4;
    int z = flat / NQ4;          // z = m*72 + q
    int m = z / 72;
    int q = z % 72;
    const float4* p4 = (const float4*)(part) + ((size_t)((m * tsplit) * 72 + q) * NF_) / 4 + idx4;
    float4 s = {0.f, 0.f, 0.f, 0.f};
    for (int ch0 = 0; ch0 < tsplit; ch0 += 10) {
        int nb = tsplit - ch0; if (nb > 10) nb = 10;
        float4 v[10];
#pragma unroll
        for (int k = 0; k < 10; ++k)
            if (k < nb) v[k] = p4[(size_t)((ch0 + k) * 72) * NF_ / 4];
        SBAR();
#pragma unroll
        for (int k = 0; k < 10; ++k)
            if (k < nb) { s.x += v[k].x; s.y += v[k].y; s.z += v[k].z; s.w += v[k].w; }
    }
    *(float4*)((float*)part + (size_t)((m * tsplit) * 72 + q) * NF_ + idx4 * 4) = s;
}

// ---------------------------------------------------------------------------
// Phase B2: wave-parallel solve (R6). One 64-lane wave per (n,f); lane (i,j)
// owns M[i][j]. GJ inverse via shuffles.
// ---------------------------------------------------------------------------
__global__ __launch_bounds__(256) void solve_w(
        const float* __restrict__ part, float* __restrict__ W, size_t yBase) {
    int widx = (blockIdx.x * 256 + threadIdx.x) >> 6;   // (n,f) index
    if (widx >= NF_) return;
    const int lane = threadIdx.x & 63;
    const int i = lane >> 3, j = lane & 7;

    const float* pv = part + widx;            // m=0, chunk 0 (reduced)
    const float* py = part + yBase + widx;    // m=1, chunk 0 (reduced)

    int a = (i > j) ? i : j, b = (i > j) ? j : i;
    int p = a*(a+1)/2 + b;
    float vr = pv[(size_t)(2*p)   * NF_] * INV_T_;
    float vi = pv[(size_t)(2*p+1) * NF_] * INV_T_;
    if (j > i) vi = -vi;                  // conj for upper triangle
    cx M { vr, vi };
    if (i == j) { M.r += LOADC_; M.i += LOADC_; }

#pragma unroll
    for (int k = 0; k < 8; ++k) {
        cx mkk { __shfl(M.r, (k<<3)|k, 64), __shfl(M.i, (k<<3)|k, 64) };
        cx mkj { __shfl(M.r, (k<<3)|j, 64), __shfl(M.i, (k<<3)|j, 64) };
        cx mik { __shfl(M.r, (i<<3)|k, 64), __shfl(M.i, (i<<3)|k, 64) };
        cx pk = cinv(mkk);
        cx rk = cmul(mkj, pk);            // normalized row-k element
        if (i == k) {
            M = (j == k) ? pk : rk;
        } else if (j == k) {
            cx t = cmul(mik, pk);
            M = { -t.r, -t.i };
        } else {
            M = csub(M, cmul(mik, rk));
        }
    }

    // trace(G) = sum_{i,j} M[i][j] * phi_y[j][i]/T
    int pt = a*(a+1)/2 + b;               // same lower-tri pair
    float yr = py[(size_t)(2*pt)   * NF_] * INV_T_;
    float yi = py[(size_t)(2*pt+1) * NF_] * INV_T_;
    if (i > j) yi = -yi;                  // phi_y[j][i], conj when j<i
    cx Yji { yr, yi };
    cx trt = cmul(M, Yji);
    float tr_r = trt.r, tr_i = trt.i;
#pragma unroll
    for (int off = 1; off < 64; off <<= 1) {
        tr_r += __shfl_xor(tr_r, off, 64);
        tr_i += __shfl_xor(tr_i, off, 64);
    }

    // g0[i] = sum_j M[i][j] * phi_y[j][0]/T  (row-reduce over j lanes)
    int p0 = j*(j+1)/2;                   // pair (j,0)
    cx y0 { py[(size_t)(2*p0)   * NF_] * INV_T_,
            py[(size_t)(2*p0+1) * NF_] * INV_T_ };
    cx g = cmul(M, y0);
#pragma unroll
    for (int off = 1; off < 8; off <<= 1) {
        g.r += __shfl_xor(g.r, off, 64);
        g.i += __shfl_xor(g.i, off, 64);
    }

    cx l { tr_r - 8.0f, tr_i - 8.0f };
    float iden = 1.0f / (l.r*l.r + l.i*l.i);
    if (j == 0) {
        cx ge = g;
        if (i == 0) ge.r -= 1.0f;
        float* w = W + (size_t)widx * 16;
        w[2*i]     = (ge.r*l.r + ge.i*l.i) * iden;   // W = conj(H)
        w[2*i + 1] = (ge.r*l.i - ge.i*l.r) * iden;
    }
}

// ---------------------------------------------------------------------------
// Phase C: beamform, float4-wide, MLP-pinned: all 16 mix loads issued
// before W loads and FMAs (previous version was sink-to-use, ~2 in flight).
// Thread owns j = 4u..4u+3 (contiguous). grid (ceil((TF/4)/256), N).
// ---------------------------------------------------------------------------
__global__ __launch_bounds__(256) void beamform(
        const float* __restrict__ mix, const float* __restrict__ W,
        float* __restrict__ out) {
    constexpr int U = TF_ / 4;   // 38550
    int n = blockIdx.y;
    int u = blockIdx.x * 256 + threadIdx.x;
    if (u >= U) return;
    int j0 = 4 * u;
    int f0 = j0 % F_;

    // Issue all 16 mix loads first (16 KB/wave in flight), pin with SBAR.
    const float* base = mix + (size_t)n * NSTR_ + j0;
    float4 y[16];
#pragma unroll
    for (int c = 0; c < C_; ++c) {
        y[c]     = *(const float4*)(base + (size_t)c * TF_);
        y[8 + c] = *(const float4*)(base + (size_t)c * TF_ + CTF_);
    }
    SBAR();

    // W rows (L2/L3-resident, 16 floats per f).
    float4 wv[4][4];
#pragma unroll
    for (int i = 0; i < 4; ++i) {
        int fi = f0 + i; if (fi >= F_) fi -= F_;
        const float4* wr = (const float4*)(W + (size_t)(n * F_ + fi) * 16);
        wv[i][0] = wr[0]; wv[i][1] = wr[1]; wv[i][2] = wr[2]; wv[i][3] = wr[3];
    }

    float xr[4] = {0.f,0.f,0.f,0.f}, xi[4] = {0.f,0.f,0.f,0.f};
#pragma unroll
    for (int c = 0; c < C_; ++c) {
        float yrA[4] = {y[c].x, y[c].y, y[c].z, y[c].w};
        float yiA[4] = {y[8+c].x, y[8+c].y, y[8+c].z, y[8+c].w};
#pragma unroll
        for (int i = 0; i < 4; ++i) {
            float wr_ = (c & 1) ? wv[i][c >> 1].z : wv[i][c >> 1].x;
            float wi_ = (c & 1) ? wv[i][c >> 1].w : wv[i][c >> 1].y;
            xr[i] += wr_*yrA[i] - wi_*yiA[i];
            xi[i] += wr_*yiA[i] + wi_*yrA[i];
        }
    }
    float* op = out + (size_t)n * (2 * TF_);
    *(float4*)(op + j0)       = make_float4(xr[0], xr[1], xr[2], xr[3]);
    *(float4*)(op + TF_ + j0) = make_float4(xi[0], xi[1], xi[2], xi[3]);
}

extern "C" void kernel_launch(void* const* d_in, const int* in_sizes, int n_in,
                              void* d_out, int out_size, void* d_ws, size_t ws_size,
                              hipStream_t stream) {
    const float* mix = (const float*)d_in[0];
    // d_in[1] = target, unused by the reference
    const float* noi = (const float*)d_in[2];

    const size_t need30 = ((size_t)2 * 30 * 72 * NF_ + (size_t)16 * NF_) * 4; // ~35.6 MB
    float* part = (float*)d_ws;
    int tsplit;
    if (ws_size >= need30) {
        tsplit = 30;   // TCHUNK=20 (div 4), 480 blocks, 1/CU (131.6 KB LDS)
        cov_partial<30><<<dim3(30, N_, 2), 320, 0, stream>>>(mix, noi, part);
    } else {
        tsplit = 25;   // TCHUNK=24 (div 4) fallback
        cov_partial<25><<<dim3(25, N_, 2), 320, 0, stream>>>(mix, noi, part);
    }
    float* W = part + (size_t)2 * tsplit * 72 * NF_;

    reduce_cov<<<dim3((2 * 72 * (NF_ / 4) + 255) / 256), 256, 0, stream>>>(part, tsplit);
    solve_w<<<dim3((NF_ * 64 + 255) / 256), 256, 0, stream>>>(part, W, (size_t)tsplit * 72 * NF_);
    beamform<<<dim3((TF_ / 4 + 255) / 256, N_), 256, 0, stream>>>(mix, W, (float*)d_out);
}